// Round 8
// baseline (297.516 us; speedup 1.0000x reference)
//
#include <hip/hip_runtime.h>
#include <stdint.h>

typedef short short8 __attribute__((ext_vector_type(8)));
typedef float f32x4 __attribute__((ext_vector_type(4)));
typedef int int2v __attribute__((ext_vector_type(2)));
typedef int int4v __attribute__((ext_vector_type(4)));

// 0.125 (1/sqrt(64)) * log2(e): fold softmax scale + exp2-domain into Q.
#define QSCALE 0.1803368801111137f
// log2(10000)/32
#define FREQC 0.4152410118609203f

__device__ __forceinline__ float bf2f(unsigned short u) {
    union { unsigned int i; float f; } x; x.i = ((unsigned int)u) << 16; return x.f;
}
__device__ __forceinline__ unsigned short f2bf(float f) {
    union { float f; unsigned int i; } x; x.f = f;
    unsigned int i = x.i;
    unsigned int r = i + 0x7FFFu + ((i >> 16) & 1u);   // RNE
    return (unsigned short)(r >> 16);
}
// packed f32x2 -> bf16x2 (RNE); no builtin on gfx950, inline asm per guide T12.
__device__ __forceinline__ int cvtpk_bf16(float lo, float hi) {
    int r;
    asm("v_cvt_pk_bf16_f32 %0, %1, %2" : "=v"(r) : "v"(lo), "v"(hi));
    return r;
}

// async global->LDS, 16B/lane. HW dest = wave-uniform base + lane*16.
#define GLDS16(g, l) \
    __builtin_amdgcn_global_load_lds((const __attribute__((address_space(1))) void*)(g), \
                                     (__attribute__((address_space(3))) void*)(l), 16, 0, 0)

// counted vmcnt waits (T4): loads stay in flight across barriers; never drain
// to 0 in the steady-state loop.
#define WAITVM(n) asm volatile("s_waitcnt vmcnt(" #n ")" ::: "memory")

// ---------------- fused fp32 -> bf16 convert for all 4 arrays (R2-measured form) ----------------
// R4-R7 merged/batched variants were all ~9us WORSE in total; this exact shape
// was part of the 285.5us best config. 16B/lane load, 8B/lane store, 24576 blocks.
__global__ void cvt_all(const float* __restrict__ hs, const float* __restrict__ k,
                        const float* __restrict__ wq, const float* __restrict__ wo,
                        unsigned short* __restrict__ hs_b, unsigned short* __restrict__ k_b,
                        unsigned short* __restrict__ wq_b, unsigned short* __restrict__ wo_b) {
    int blk = blockIdx.x;
    const float* in; unsigned short* out; int i;
    if (blk < 8192)        { in = hs; out = hs_b; i = blk * 256 + threadIdx.x; }
    else if (blk < 16384)  { in = k;  out = k_b;  i = (blk - 8192) * 256 + threadIdx.x; }
    else if (blk < 20480)  { in = wq; out = wq_b; i = (blk - 16384) * 256 + threadIdx.x; }
    else                   { in = wo; out = wo_b; i = (blk - 20480) * 256 + threadIdx.x; }
    float4 v = ((const float4*)in)[i];
    ushort4 o;
    o.x = f2bf(v.x); o.y = f2bf(v.y); o.z = f2bf(v.z); o.w = f2bf(v.w);
    ((ushort4*)out)[i] = o;
}

// ---------------- V: (B,T,H,D) f32 -> (B,H,D,T) bf16 (R2-measured form) ----------------
__global__ __launch_bounds__(256) void transpose_v(const float* __restrict__ V, unsigned short* __restrict__ Vt) {
    __shared__ float s[64 * 65];
    int t0 = blockIdx.x * 64;
    int bh = blockIdx.y;           // b*32 + h
    int b = bh >> 5, h = bh & 31;
    int tid = threadIdx.x;
#pragma unroll
    for (int it = 0; it < 4; ++it) {
        int c = tid + it * 256;
        int t = c >> 4;
        int d0 = (c & 15) * 4;
        float4 v = *(const float4*)(V + (size_t)(((b * 2048 + t0 + t) * 32 + h)) * 64 + d0);
        s[t * 65 + d0 + 0] = v.x; s[t * 65 + d0 + 1] = v.y;
        s[t * 65 + d0 + 2] = v.z; s[t * 65 + d0 + 3] = v.w;
    }
    __syncthreads();
#pragma unroll
    for (int it = 0; it < 2; ++it) {
        int c = tid + it * 256;
        int d = c >> 3;
        int tt = (c & 7) * 8;
        short8 pk;
#pragma unroll
        for (int j = 0; j < 8; ++j) pk[j] = (short)f2bf(s[(tt + j) * 65 + d]);
        *(short8*)(Vt + (size_t)(bh * 64 + d) * 2048 + t0 + tt) = pk;
    }
}

// ---------------- bf16 GEMM, C = A * B^T; 128x128 tile, BK=64, 4 waves ----------------
// R2-best structure (285.5 total): 2-buffer, counted vmcnt(8), raw barriers.
// R4-R6 256x128/3-buf/phase-split experiments were all ~8us worse (tile choice
// is structure-dependent, m105/m201). Keeping the empirical best.
template <bool BF16_OUT>
__global__ __launch_bounds__(256) void gemm_bt(
    const unsigned short* __restrict__ A,   // M x K bf16
    const unsigned short* __restrict__ B,   // N x K bf16
    void* __restrict__ Cout,                // M x N
    int M, int N, int K)
{
    __shared__ __align__(16) unsigned short lA[2][128 * 64];
    __shared__ __align__(16) unsigned short lB[2][128 * 64];
    int tid = threadIdx.x, lane = tid & 63, wave = tid >> 6;
    int wm = (wave >> 1) * 64, wn = (wave & 1) * 64;
    int m16 = lane & 15, q = lane >> 4;
    int rowBase = blockIdx.x * 128, colBase = blockIdx.y * 128;
    f32x4 acc[4][4] = {};

    int sr = lane >> 3;            // 0..7: row within 8-row group
    int g  = (lane & 7) ^ sr;      // swizzled k-group
    const unsigned short* gAp = A + (size_t)(rowBase + wave * 32 + sr) * K + g * 8;
    const unsigned short* gBp = B + (size_t)(colBase + wave * 32 + sr) * K + g * 8;

#define GSTAGE(buf, k0)                                                                      \
    do {                                                                                     \
        _Pragma("unroll")                                                                    \
        for (int gi = 0; gi < 4; ++gi) {                                                     \
            GLDS16(gAp + (size_t)(8 * gi) * K + (k0), &lA[buf][(wave * 32 + 8 * gi) * 64]);  \
            GLDS16(gBp + (size_t)(8 * gi) * K + (k0), &lB[buf][(wave * 32 + 8 * gi) * 64]);  \
        }                                                                                    \
    } while (0)

    GSTAGE(0, 0);
    WAITVM(0);
    __builtin_amdgcn_s_barrier();
    int cur = 0;
    for (int k0 = 0; k0 < K; k0 += 64) {
        if (k0 + 64 < K) {
            GSTAGE(cur ^ 1, k0 + 64);   // 8 loads stay in flight through compute
            WAITVM(8);                  // tile-k0's 8 (oldest) have landed
        } else {
            WAITVM(0);                  // final tile: full drain
        }
        __builtin_amdgcn_s_barrier();   // all waves' tile-k0 loads complete
        const unsigned short* la = lA[cur];
        const unsigned short* lb = lB[cur];
#pragma unroll
        for (int kk = 0; kk < 2; ++kk) {
            short8 af[4], bfr[4];
#pragma unroll
            for (int i2 = 0; i2 < 4; ++i2) {
                int RA = wm + i2 * 16 + m16;
                af[i2]  = *(const short8*)&la[RA * 64 + (((kk * 4 + q) ^ (RA & 7)) * 8)];
                int RB = wn + i2 * 16 + m16;
                bfr[i2] = *(const short8*)&lb[RB * 64 + (((kk * 4 + q) ^ (RB & 7)) * 8)];
            }
#pragma unroll
            for (int i2 = 0; i2 < 4; ++i2)
#pragma unroll
                for (int jn = 0; jn < 4; ++jn)
                    acc[i2][jn] = __builtin_amdgcn_mfma_f32_16x16x32_bf16(af[i2], bfr[jn], acc[i2][jn], 0, 0, 0);
        }
        __builtin_amdgcn_s_barrier();   // reads done before next iter overwrites buf^1
        cur ^= 1;
    }
#pragma unroll
    for (int i = 0; i < 4; ++i)
#pragma unroll
        for (int jn = 0; jn < 4; ++jn)
#pragma unroll
            for (int r = 0; r < 4; ++r) {
                int row = rowBase + wm + i * 16 + q * 4 + r;   // C row = quad*4+reg
                int col = colBase + wn + jn * 16 + m16;        // C col = lane&15
                float v = acc[i][jn][r];
                if (BF16_OUT) ((unsigned short*)Cout)[(size_t)row * N + col] = f2bf(v);
                else          ((float*)Cout)[(size_t)row * N + col] = v;
            }
}

// ---------------- flash attention (causal), paired Q-tiles, RoPE fused ----------------
// NEW this round: 3-buffer K/V staging with ONE barrier per K-tile (was 2-buf,
// 2 barriers). Safety proof: at iter kt, ASTAGE writes buf[(kt+1)%3], whose
// last readers were COMPUTE(kt-2). In program order COMPUTE(kt-2) precedes
// BARRIER(kt-1); since this wave has passed BARRIER(kt-1), all waves completed
// COMPUTE(kt-2) -> no WAR race. (With 2 buffers ASTAGE would target the buffer
// other waves may still be computing from -> the old trailing barrier.)
// m233: stage+wait+barrier is ~72% of a 2-phase loop's cost; halving barrier
// count attacks that directly. LDS 48KB -> 3 blocks/CU (measured residency was
// only ~2.6 anyway, Occ 33%).
// Swapped QK^T (mfma(K,Q)) => lane (q,m16) holds P[key=nt*16+q*4+r][query=m16].
// PV uses a permuted key order applied to BOTH operands, making the PV
// A-fragment the lane's OWN exp2 results packed via v_cvt_pk_bf16_f32 -- no sP
// LDS, no cross-lane ops.
__global__ __launch_bounds__(256, 3) void attn(
    const unsigned short* __restrict__ Q,   // (B*T) x 2048, raw gemm1 output (no rope)
    const unsigned short* __restrict__ Kb,  // (B*T) x 2048
    const unsigned short* __restrict__ Vt,  // (B*H*64) x 2048  (d-major)
    unsigned short* __restrict__ O)         // (B*T) x 2048
{
    __shared__ __align__(16) unsigned short sK[3][64 * 64];   // rows = key, cols = d (swizzled)
    __shared__ __align__(16) unsigned short sV[3][64 * 64];   // rows = d, cols = key (swizzled)
    int tid = threadIdx.x, lane = tid & 63, w = tid >> 6;
    int m16 = lane & 15, q = lane >> 4;
    int rx = m16 & 7;                        // row&7 for all LDS reads (rows = nt*16+m16)
    int flat = blockIdx.x;
    int bh = flat & 63, p = flat >> 6;       // flat%8==bh%8 -> (b,h) pinned to one XCD
    int b = bh >> 5, h = bh & 31;
    int qtA = 31 - p, qtB = p;

    // Q fragments for both tiles: load, RoPE (interleaved pairs are frag-local), scale.
    short8 aqA0, aqA1, aqB0, aqB1;
    {
        int tA = qtA * 64 + w * 16 + m16;
        int tB = qtB * 64 + w * 16 + m16;
        const unsigned short* rowA = Q + (size_t)(b * 2048 + tA) * 2048 + h * 64 + q * 8;
        const unsigned short* rowB = Q + (size_t)(b * 2048 + tB) * 2048 + h * 64 + q * 8;
        short8 a0 = *(const short8*)rowA, a1 = *(const short8*)(rowA + 32);
        short8 b0 = *(const short8*)rowB, b1 = *(const short8*)(rowB + 32);
        float tfA = (float)tA, tfB = (float)tB;
#pragma unroll
        for (int j = 0; j < 4; ++j) {
            float inv0 = __builtin_amdgcn_exp2f(-FREQC * (float)(q * 4 + j));
            float inv1 = __builtin_amdgcn_exp2f(-FREQC * (float)(16 + q * 4 + j));
            float cA0 = __cosf(tfA * inv0), sA0 = __sinf(tfA * inv0);
            float cA1 = __cosf(tfA * inv1), sA1 = __sinf(tfA * inv1);
            float cB0 = __cosf(tfB * inv0), sB0 = __sinf(tfB * inv0);
            float cB1 = __cosf(tfB * inv1), sB1 = __sinf(tfB * inv1);
            float x1, x2;
            x1 = bf2f((unsigned short)a0[2 * j]); x2 = bf2f((unsigned short)a0[2 * j + 1]);
            aqA0[2 * j]     = (short)f2bf((x1 * cA0 - x2 * sA0) * QSCALE);
            aqA0[2 * j + 1] = (short)f2bf((x1 * sA0 + x2 * cA0) * QSCALE);
            x1 = bf2f((unsigned short)a1[2 * j]); x2 = bf2f((unsigned short)a1[2 * j + 1]);
            aqA1[2 * j]     = (short)f2bf((x1 * cA1 - x2 * sA1) * QSCALE);
            aqA1[2 * j + 1] = (short)f2bf((x1 * sA1 + x2 * cA1) * QSCALE);
            x1 = bf2f((unsigned short)b0[2 * j]); x2 = bf2f((unsigned short)b0[2 * j + 1]);
            aqB0[2 * j]     = (short)f2bf((x1 * cB0 - x2 * sB0) * QSCALE);
            aqB0[2 * j + 1] = (short)f2bf((x1 * sB0 + x2 * cB0) * QSCALE);
            x1 = bf2f((unsigned short)b1[2 * j]); x2 = bf2f((unsigned short)b1[2 * j + 1]);
            aqB1[2 * j]     = (short)f2bf((x1 * cB1 - x2 * sB1) * QSCALE);
            aqB1[2 * j + 1] = (short)f2bf((x1 * sB1 + x2 * cB1) * QSCALE);
        }
    }

    float lrunA = 0.f, lrunB = 0.f;          // per-lane denominator partial for query m16
    f32x4 accOA[4], accOB[4];
#pragma unroll
    for (int nt = 0; nt < 4; ++nt) {
        f32x4 z = {0.f, 0.f, 0.f, 0.f};
        accOA[nt] = z; accOB[nt] = z;
    }

    // staging: wave w stages K rows / V d-rows [w*16, w*16+16). 8 rows per GLDS.
    // swizzle: slot (lane&7) holds global col-group (lane&7)^sr, sr = row&7.
    int sr = lane >> 3, g = (lane & 7) ^ sr;
    int rb = w * 16;
    const unsigned short* kgp = Kb + (size_t)(b * 2048 + rb + sr) * 2048 + h * 64 + g * 8;
    const unsigned short* vgp = Vt + (size_t)((b * 32 + h) * 64 + rb + sr) * 2048 + g * 8;

#define ASTAGE(kt, bi)                                                                \
    do {                                                                              \
        int kb0 = (kt) * 64;                                                          \
        _Pragma("unroll")                                                             \
        for (int gi = 0; gi < 2; ++gi) {                                              \
            GLDS16(kgp + (size_t)(kb0 + 8 * gi) * 2048, &sK[bi][(rb + 8 * gi) * 64]); \
            GLDS16(vgp + (size_t)(8 * gi) * 2048 + kb0, &sV[bi][(rb + 8 * gi) * 64]); \
        }                                                                             \
    } while (0)

    ASTAGE(0, 0);
    WAITVM(0);
    __builtin_amdgcn_s_barrier();
    int cur = 0, nxt = 1;
    for (int kt = 0; kt <= qtA; ++kt) {
        if (kt < qtA) {
            ASTAGE(kt + 1, nxt);        // 4 loads stay in flight through compute
            WAITVM(4);                  // tile-kt's 4 (oldest) have landed
        } else {
            WAITVM(0);
        }
        __builtin_amdgcn_s_barrier();   // the ONLY barrier per iteration (3-buf proof above)
        bool doB = (kt <= qtB);
        bool diagA = (kt == qtA), diagB = (kt == qtB);
        const unsigned short* kbuf = sK[cur];
        const unsigned short* vbuf = sV[cur];

        // ---- QK^T (swapped) + softmax, P packed in registers ----
        int pkA[4][2], pkB[4][2];
#pragma unroll
        for (int nt = 0; nt < 4; ++nt) {
            const unsigned short* kr = kbuf + (nt * 16 + m16) * 64;
            short8 bk0 = *(const short8*)&kr[(q ^ rx) * 8];          // dims 0..31, slice q*8
            short8 bk1 = *(const short8*)&kr[((4 + q) ^ rx) * 8];    // dims 32..63
            f32x4 zA = {0.f, 0.f, 0.f, 0.f};
            zA = __builtin_amdgcn_mfma_f32_16x16x32_bf16(bk0, aqA0, zA, 0, 0, 0);
            zA = __builtin_amdgcn_mfma_f32_16x16x32_bf16(bk1, aqA1, zA, 0, 0, 0);
            float e[4];
#pragma unroll
            for (int r = 0; r < 4; ++r) {
                float s = zA[r];                                      // P[key nt*16+q*4+r][query m16]
                if (diagA && (nt * 16 + q * 4 + r > w * 16 + m16)) s = -__builtin_inff();
                e[r] = __builtin_amdgcn_exp2f(s);
            }
            lrunA += (e[0] + e[1]) + (e[2] + e[3]);
            pkA[nt][0] = cvtpk_bf16(e[0], e[1]);
            pkA[nt][1] = cvtpk_bf16(e[2], e[3]);
            if (doB) {
                f32x4 zB = {0.f, 0.f, 0.f, 0.f};
                zB = __builtin_amdgcn_mfma_f32_16x16x32_bf16(bk0, aqB0, zB, 0, 0, 0);
                zB = __builtin_amdgcn_mfma_f32_16x16x32_bf16(bk1, aqB1, zB, 0, 0, 0);
                float eb[4];
#pragma unroll
                for (int r = 0; r < 4; ++r) {
                    float s = zB[r];
                    if (diagB && (nt * 16 + q * 4 + r > w * 16 + m16)) s = -__builtin_inff();
                    eb[r] = __builtin_amdgcn_exp2f(s);
                }
                lrunB += (eb[0] + eb[1]) + (eb[2] + eb[3]);
                pkB[nt][0] = cvtpk_bf16(eb[0], eb[1]);
                pkB[nt][1] = cvtpk_bf16(eb[2], eb[3]);
            }
        }

        // PV A-fragments: permuted key order makes them the lane's own packed values.
        int4v tA0 = {pkA[0][0], pkA[0][1], pkA[1][0], pkA[1][1]};
        int4v tA1 = {pkA[2][0], pkA[2][1], pkA[3][0], pkA[3][1]};
        short8 apA0 = __builtin_bit_cast(short8, tA0);
        short8 apA1 = __builtin_bit_cast(short8, tA1);
        short8 apB0, apB1;
        if (doB) {
            int4v tB0 = {pkB[0][0], pkB[0][1], pkB[1][0], pkB[1][1]};
            int4v tB1 = {pkB[2][0], pkB[2][1], pkB[3][0], pkB[3][1]};
            apB0 = __builtin_bit_cast(short8, tB0);
            apB1 = __builtin_bit_cast(short8, tB1);
        }

        // ---- PV: V fragment at permuted key columns, 4x ds_read_b64 per d-tile ----
#pragma unroll
        for (int nt = 0; nt < 4; ++nt) {
            const unsigned short* vr = vbuf + (nt * 16 + m16) * 64;   // row = d
            int2v a0 = *(const int2v*)&vr[(((q >> 1) + 0) ^ rx) * 8 + (q & 1) * 4]; // keys q*4+0..3
            int2v a1 = *(const int2v*)&vr[(((q >> 1) + 2) ^ rx) * 8 + (q & 1) * 4]; // keys 16+q*4..
            int2v a2 = *(const int2v*)&vr[(((q >> 1) + 4) ^ rx) * 8 + (q & 1) * 4]; // keys 32+q*4..
            int2v a3 = *(const int2v*)&vr[(((q >> 1) + 6) ^ rx) * 8 + (q & 1) * 4]; // keys 48+q*4..
            int4v tv0 = {a0.x, a0.y, a1.x, a1.y};
            int4v tv1 = {a2.x, a2.y, a3.x, a3.y};
            short8 bv0 = __builtin_bit_cast(short8, tv0);
            short8 bv1 = __builtin_bit_cast(short8, tv1);
            accOA[nt] = __builtin_amdgcn_mfma_f32_16x16x32_bf16(apA0, bv0, accOA[nt], 0, 0, 0);
            accOA[nt] = __builtin_amdgcn_mfma_f32_16x16x32_bf16(apA1, bv1, accOA[nt], 0, 0, 0);
            if (doB) {
                accOB[nt] = __builtin_amdgcn_mfma_f32_16x16x32_bf16(apB0, bv0, accOB[nt], 0, 0, 0);
                accOB[nt] = __builtin_amdgcn_mfma_f32_16x16x32_bf16(apB1, bv1, accOB[nt], 0, 0, 0);
            }
        }
        // no trailing barrier: 3-buffer rotation makes next iter's ASTAGE target
        // a buffer whose readers are provably done (see header comment).
        cur = (cur == 2) ? 0 : cur + 1;
        nxt = (nxt == 2) ? 0 : nxt + 1;
    }

    // denominator: reduce over the 4 q-lanes holding the same query (xor bits 4,5),
    // then redistribute 1/l from query=m16 ownership to the output rows q*4+r.
    lrunA += __shfl_xor(lrunA, 16); lrunA += __shfl_xor(lrunA, 32);
    lrunB += __shfl_xor(lrunB, 16); lrunB += __shfl_xor(lrunB, 32);
    float invA = 1.0f / lrunA, invB = 1.0f / lrunB;
    float nA[4], nB[4];
#pragma unroll
    for (int r = 0; r < 4; ++r) {
        nA[r] = __shfl(invA, q * 4 + r);
        nB[r] = __shfl(invB, q * 4 + r);
    }
#pragma unroll
    for (int nt = 0; nt < 4; ++nt)
#pragma unroll
        for (int r = 0; r < 4; ++r) {
            int col = h * 64 + nt * 16 + m16;
            O[(size_t)(b * 2048 + qtA * 64 + w * 16 + q * 4 + r) * 2048 + col] =
                f2bf(accOA[nt][r] * nA[r]);
            O[(size_t)(b * 2048 + qtB * 64 + w * 16 + q * 4 + r) * 2048 + col] =
                f2bf(accOB[nt][r] * nB[r]);
        }
}

// ---------------- host launcher ----------------
extern "C" void kernel_launch(void* const* d_in, const int* in_sizes, int n_in,
                              void* d_out, int out_size, void* d_ws, size_t ws_size,
                              hipStream_t stream) {
    const float* hs = (const float*)d_in[0];   // (2,2048,2048)
    const float* sk = (const float*)d_in[1];   // (2,2048,32,64)
    const float* sv = (const float*)d_in[2];   // (2,2048,32,64)
    const float* wq = (const float*)d_in[3];   // (2048,2048)
    const float* wo = (const float*)d_in[4];   // (2048,2048)
    float* out = (float*)d_out;

    char* ws = (char*)d_ws;
    unsigned short* hid_b = (unsigned short*)(ws);                              // 16 MiB
    unsigned short* wq_b  = (unsigned short*)(ws + ((size_t)16 << 20));         //  8 MiB
    unsigned short* wo_b  = (unsigned short*)(ws + ((size_t)24 << 20));         //  8 MiB
    unsigned short* k_b   = (unsigned short*)(ws + ((size_t)32 << 20));         // 16 MiB
    unsigned short* vt_b  = (unsigned short*)(ws + ((size_t)48 << 20));         // 16 MiB
    unsigned short* q_b   = (unsigned short*)(ws + ((size_t)64 << 20));         // 16 MiB
    unsigned short* o_b   = (unsigned short*)(ws + ((size_t)80 << 20));         // 16 MiB

    cvt_all<<<24576, 256, 0, stream>>>(hs, sk, wq, wo, hid_b, k_b, wq_b, wo_b);
    transpose_v<<<dim3(32, 64), 256, 0, stream>>>(sv, vt_b);
    gemm_bt<true><<<dim3(32, 16), 256, 0, stream>>>(hid_b, wq_b, (void*)q_b, 4096, 2048, 2048);
    attn<<<1024, 256, 0, stream>>>(q_b, k_b, vt_b, o_b);
    gemm_bt<false><<<dim3(32, 16), 256, 0, stream>>>(o_b, wo_b, (void*)out, 4096, 2048, 2048);
}

// Round 9
// 294.128 us; speedup vs baseline: 1.0115x; 1.0115x over previous
//
#include <hip/hip_runtime.h>
#include <stdint.h>

typedef short short8 __attribute__((ext_vector_type(8)));
typedef float f32x4 __attribute__((ext_vector_type(4)));
typedef int int2v __attribute__((ext_vector_type(2)));
typedef int int4v __attribute__((ext_vector_type(4)));

// 0.125 (1/sqrt(64)) * log2(e): fold softmax scale + exp2-domain into Q.
#define QSCALE 0.1803368801111137f
// log2(10000)/32
#define FREQC 0.4152410118609203f

__device__ __forceinline__ float bf2f(unsigned short u) {
    union { unsigned int i; float f; } x; x.i = ((unsigned int)u) << 16; return x.f;
}
__device__ __forceinline__ unsigned short f2bf(float f) {
    union { float f; unsigned int i; } x; x.f = f;
    unsigned int i = x.i;
    unsigned int r = i + 0x7FFFu + ((i >> 16) & 1u);   // RNE
    return (unsigned short)(r >> 16);
}
// packed f32x2 -> bf16x2 (RNE); no builtin on gfx950, inline asm per guide T12.
__device__ __forceinline__ int cvtpk_bf16(float lo, float hi) {
    int r;
    asm("v_cvt_pk_bf16_f32 %0, %1, %2" : "=v"(r) : "v"(lo), "v"(hi));
    return r;
}

// async global->LDS, 16B/lane. HW dest = wave-uniform base + lane*16.
#define GLDS16(g, l) \
    __builtin_amdgcn_global_load_lds((const __attribute__((address_space(1))) void*)(g), \
                                     (__attribute__((address_space(3))) void*)(l), 16, 0, 0)

// counted vmcnt waits (T4): loads stay in flight across barriers; never drain
// to 0 in the steady-state loop.
#define WAITVM(n) asm volatile("s_waitcnt vmcnt(" #n ")" ::: "memory")

// ---------------- fused fp32->bf16 convert (4 arrays) + V transpose (R2-measured form) ----------------
// blocks [0,24576): elementwise cvt 16B/lane; blocks [24576,26624): V transpose.
__global__ __launch_bounds__(256) void cvt_tr(
    const float* __restrict__ hs, const float* __restrict__ k,
    const float* __restrict__ wq, const float* __restrict__ wo,
    const float* __restrict__ V,
    unsigned short* __restrict__ hs_b, unsigned short* __restrict__ k_b,
    unsigned short* __restrict__ wq_b, unsigned short* __restrict__ wo_b,
    unsigned short* __restrict__ Vt) {
    __shared__ float s[64 * 65];
    int blk = blockIdx.x;
    int tid = threadIdx.x;
    if (blk < 24576) {
        const float* in; unsigned short* out; int i;
        if (blk < 8192)        { in = hs; out = hs_b; i = blk * 256 + tid; }
        else if (blk < 16384)  { in = k;  out = k_b;  i = (blk - 8192) * 256 + tid; }
        else if (blk < 20480)  { in = wq; out = wq_b; i = (blk - 16384) * 256 + tid; }
        else                   { in = wo; out = wo_b; i = (blk - 20480) * 256 + tid; }
        float4 v = ((const float4*)in)[i];
        ushort4 o;
        o.x = f2bf(v.x); o.y = f2bf(v.y); o.z = f2bf(v.z); o.w = f2bf(v.w);
        ((ushort4*)out)[i] = o;
        return;
    }
    int tb = blk - 24576;          // 0..2047
    int t0 = (tb & 31) * 64;
    int bh = tb >> 5;              // b*32 + h
    int b = bh >> 5, h = bh & 31;
#pragma unroll
    for (int it = 0; it < 4; ++it) {
        int c = tid + it * 256;
        int t = c >> 4;
        int d0 = (c & 15) * 4;
        float4 v = *(const float4*)(V + (size_t)(((b * 2048 + t0 + t) * 32 + h)) * 64 + d0);
        s[t * 65 + d0 + 0] = v.x; s[t * 65 + d0 + 1] = v.y;
        s[t * 65 + d0 + 2] = v.z; s[t * 65 + d0 + 3] = v.w;
    }
    __syncthreads();
#pragma unroll
    for (int it = 0; it < 2; ++it) {
        int c = tid + it * 256;
        int d = c >> 3;
        int tt = (c & 7) * 8;
        short8 pk;
#pragma unroll
        for (int j = 0; j < 8; ++j) pk[j] = (short)f2bf(s[(tt + j) * 65 + d]);
        *(short8*)(Vt + (size_t)(bh * 64 + d) * 2048 + t0 + tt) = pk;
    }
}

// ---------------- bf16 GEMM, C = A * B^T; 128x128 tile, BK=64, 4 waves (R2-measured form) ----------------
// 2-buffer, counted vmcnt(8), raw barriers. R4-R6 bigger-tile/3-buf/phase-split
// variants were all ~8us worse at this shape. Keeping the empirical best.
template <bool BF16_OUT>
__global__ __launch_bounds__(256) void gemm_bt(
    const unsigned short* __restrict__ A,   // M x K bf16
    const unsigned short* __restrict__ B,   // N x K bf16
    void* __restrict__ Cout,                // M x N
    int M, int N, int K)
{
    __shared__ __align__(16) unsigned short lA[2][128 * 64];
    __shared__ __align__(16) unsigned short lB[2][128 * 64];
    int tid = threadIdx.x, lane = tid & 63, wave = tid >> 6;
    int wm = (wave >> 1) * 64, wn = (wave & 1) * 64;
    int m16 = lane & 15, q = lane >> 4;
    int rowBase = blockIdx.x * 128, colBase = blockIdx.y * 128;
    f32x4 acc[4][4] = {};

    int sr = lane >> 3;            // 0..7: row within 8-row group
    int g  = (lane & 7) ^ sr;      // swizzled k-group
    const unsigned short* gAp = A + (size_t)(rowBase + wave * 32 + sr) * K + g * 8;
    const unsigned short* gBp = B + (size_t)(colBase + wave * 32 + sr) * K + g * 8;

#define GSTAGE(buf, k0)                                                                      \
    do {                                                                                     \
        _Pragma("unroll")                                                                    \
        for (int gi = 0; gi < 4; ++gi) {                                                     \
            GLDS16(gAp + (size_t)(8 * gi) * K + (k0), &lA[buf][(wave * 32 + 8 * gi) * 64]);  \
            GLDS16(gBp + (size_t)(8 * gi) * K + (k0), &lB[buf][(wave * 32 + 8 * gi) * 64]);  \
        }                                                                                    \
    } while (0)

    GSTAGE(0, 0);
    WAITVM(0);
    __builtin_amdgcn_s_barrier();
    int cur = 0;
    for (int k0 = 0; k0 < K; k0 += 64) {
        if (k0 + 64 < K) {
            GSTAGE(cur ^ 1, k0 + 64);   // 8 loads stay in flight through compute
            WAITVM(8);                  // tile-k0's 8 (oldest) have landed
        } else {
            WAITVM(0);                  // final tile: full drain
        }
        __builtin_amdgcn_s_barrier();   // all waves' tile-k0 loads complete
        const unsigned short* la = lA[cur];
        const unsigned short* lb = lB[cur];
#pragma unroll
        for (int kk = 0; kk < 2; ++kk) {
            short8 af[4], bfr[4];
#pragma unroll
            for (int i2 = 0; i2 < 4; ++i2) {
                int RA = wm + i2 * 16 + m16;
                af[i2]  = *(const short8*)&la[RA * 64 + (((kk * 4 + q) ^ (RA & 7)) * 8)];
                int RB = wn + i2 * 16 + m16;
                bfr[i2] = *(const short8*)&lb[RB * 64 + (((kk * 4 + q) ^ (RB & 7)) * 8)];
            }
#pragma unroll
            for (int i2 = 0; i2 < 4; ++i2)
#pragma unroll
                for (int jn = 0; jn < 4; ++jn)
                    acc[i2][jn] = __builtin_amdgcn_mfma_f32_16x16x32_bf16(af[i2], bfr[jn], acc[i2][jn], 0, 0, 0);
        }
        __builtin_amdgcn_s_barrier();   // reads done before next iter overwrites buf^1
        cur ^= 1;
    }
#pragma unroll
    for (int i = 0; i < 4; ++i)
#pragma unroll
        for (int jn = 0; jn < 4; ++jn)
#pragma unroll
            for (int r = 0; r < 4; ++r) {
                int row = rowBase + wm + i * 16 + q * 4 + r;   // C row = quad*4+reg
                int col = colBase + wn + jn * 16 + m16;        // C col = lane&15
                float v = acc[i][jn][r];
                if (BF16_OUT) ((unsigned short*)Cout)[(size_t)row * N + col] = f2bf(v);
                else          ((float*)Cout)[(size_t)row * N + col] = v;
            }
}

// ---------------- flash attention (causal), FOUR Q-tiles per block, RoPE fused ----------------
// NEW: 4 Q-tiles {31-p, 16+p, 15-p, p} per block (p in [0,8)), 512 blocks.
// Each block's causal work = 66 tile-computes (balanced); staged K/V tiles drop
// 42% grid-wide and bk/bv LDS fragment reads are shared 4-ways (was 2).
// Residency constraint from R8's failure: LDS stays 32KB (2-buf), grid 512 =
// 2 blocks/CU, ALL blocks resident (VGPR ~200 -> 2 waves/SIMD = 8 waves/CU ==
// 2 blocks x 4 waves: consistent). XCD pinning kept: flat%8 == bh%8.
// Core layout (unchanged): swapped QK^T => lane (q,m16) holds
// P[key=nt*16+q*4+r][query=m16]; PV A-fragment is the lane's own packed exp2
// results via v_cvt_pk_bf16_f32 under a both-operand key permutation.
// 2-buf staging, counted vmcnt(4), raw barriers (R2-proven form).
__global__ __launch_bounds__(256, 2) void attn(
    const unsigned short* __restrict__ Q,   // (B*T) x 2048, raw gemm1 output (no rope)
    const unsigned short* __restrict__ Kb,  // (B*T) x 2048
    const unsigned short* __restrict__ Vt,  // (B*H*64) x 2048  (d-major)
    unsigned short* __restrict__ O)         // (B*T) x 2048
{
    __shared__ __align__(16) unsigned short sK[2][64 * 64];   // rows = key, cols = d (swizzled)
    __shared__ __align__(16) unsigned short sV[2][64 * 64];   // rows = d, cols = key (swizzled)
    int tid = threadIdx.x, lane = tid & 63, w = tid >> 6;
    int m16 = lane & 15, q = lane >> 4;
    int rx = m16 & 7;                        // row&7 for all LDS reads (rows = nt*16+m16)
    int flat = blockIdx.x;
    int bh = flat & 63, p = flat >> 6;       // p in [0,8); flat%8==bh%8 -> XCD pinned
    int b = bh >> 5, h = bh & 31;
    int tA = 31 - p, tB = 16 + p, tC = 15 - p, tD = p;   // causal costs sum to 66 for every p

    // Q fragments for 4 tiles: load, RoPE (interleaved pairs are frag-local), scale.
    short8 aqA0, aqA1, aqB0, aqB1, aqC0, aqC1, aqD0, aqD1;
    {
        int rA = tA * 64 + w * 16 + m16, rB = tB * 64 + w * 16 + m16;
        int rC = tC * 64 + w * 16 + m16, rD = tD * 64 + w * 16 + m16;
        const unsigned short* pA = Q + (size_t)(b * 2048 + rA) * 2048 + h * 64 + q * 8;
        const unsigned short* pB = Q + (size_t)(b * 2048 + rB) * 2048 + h * 64 + q * 8;
        const unsigned short* pC = Q + (size_t)(b * 2048 + rC) * 2048 + h * 64 + q * 8;
        const unsigned short* pD = Q + (size_t)(b * 2048 + rD) * 2048 + h * 64 + q * 8;
        short8 a0 = *(const short8*)pA, a1 = *(const short8*)(pA + 32);
        short8 b0 = *(const short8*)pB, b1 = *(const short8*)(pB + 32);
        short8 c0 = *(const short8*)pC, c1 = *(const short8*)(pC + 32);
        short8 d0 = *(const short8*)pD, d1 = *(const short8*)(pD + 32);
        float tfA = (float)rA, tfB = (float)rB, tfC = (float)rC, tfD = (float)rD;
#pragma unroll
        for (int j = 0; j < 4; ++j) {
            float inv0 = __builtin_amdgcn_exp2f(-FREQC * (float)(q * 4 + j));
            float inv1 = __builtin_amdgcn_exp2f(-FREQC * (float)(16 + q * 4 + j));
            float x1, x2, cc, ss;
#define ROPE1(dst, src, tf, inv)                                          \
            cc = __cosf((tf) * (inv)); ss = __sinf((tf) * (inv));         \
            x1 = bf2f((unsigned short)src[2 * j]);                        \
            x2 = bf2f((unsigned short)src[2 * j + 1]);                    \
            dst[2 * j]     = (short)f2bf((x1 * cc - x2 * ss) * QSCALE);   \
            dst[2 * j + 1] = (short)f2bf((x1 * ss + x2 * cc) * QSCALE)
            ROPE1(aqA0, a0, tfA, inv0); ROPE1(aqA1, a1, tfA, inv1);
            ROPE1(aqB0, b0, tfB, inv0); ROPE1(aqB1, b1, tfB, inv1);
            ROPE1(aqC0, c0, tfC, inv0); ROPE1(aqC1, c1, tfC, inv1);
            ROPE1(aqD0, d0, tfD, inv0); ROPE1(aqD1, d1, tfD, inv1);
#undef ROPE1
        }
    }

    float lrunA = 0.f, lrunB = 0.f, lrunC = 0.f, lrunD = 0.f;
    f32x4 accOA[4], accOB[4], accOC[4], accOD[4];
#pragma unroll
    for (int nt = 0; nt < 4; ++nt) {
        f32x4 z = {0.f, 0.f, 0.f, 0.f};
        accOA[nt] = z; accOB[nt] = z; accOC[nt] = z; accOD[nt] = z;
    }

    // staging: wave w stages K rows / V d-rows [w*16, w*16+16). 8 rows per GLDS.
    // swizzle: slot (lane&7) holds global col-group (lane&7)^sr, sr = row&7.
    int sr = lane >> 3, g = (lane & 7) ^ sr;
    int rb = w * 16;
    const unsigned short* kgp = Kb + (size_t)(b * 2048 + rb + sr) * 2048 + h * 64 + g * 8;
    const unsigned short* vgp = Vt + (size_t)((b * 32 + h) * 64 + rb + sr) * 2048 + g * 8;

#define ASTAGE(kt, bi)                                                                \
    do {                                                                              \
        int kb0 = (kt) * 64;                                                          \
        _Pragma("unroll")                                                             \
        for (int gi = 0; gi < 2; ++gi) {                                              \
            GLDS16(kgp + (size_t)(kb0 + 8 * gi) * 2048, &sK[bi][(rb + 8 * gi) * 64]); \
            GLDS16(vgp + (size_t)(8 * gi) * 2048 + kb0, &sV[bi][(rb + 8 * gi) * 64]); \
        }                                                                             \
    } while (0)

    ASTAGE(0, 0);
    WAITVM(0);
    __builtin_amdgcn_s_barrier();
    int cur = 0;
    for (int kt = 0; kt <= tA; ++kt) {
        if (kt < tA) {
            ASTAGE(kt + 1, cur ^ 1);    // 4 loads stay in flight through compute
            WAITVM(4);                  // tile-kt's 4 (oldest) have landed
        } else {
            WAITVM(0);
        }
        __builtin_amdgcn_s_barrier();
        bool doB = (kt <= tB), doC = (kt <= tC), doD = (kt <= tD);
        bool dgA = (kt == tA), dgB = (kt == tB), dgC = (kt == tC), dgD = (kt == tD);
        const unsigned short* kbuf = sK[cur];
        const unsigned short* vbuf = sV[cur];

        // ---- QK^T (swapped) + softmax, P packed in registers; bk shared 4-ways ----
        int pkA[4][2], pkB[4][2], pkC[4][2], pkD[4][2];
#pragma unroll
        for (int nt = 0; nt < 4; ++nt) {
            const unsigned short* kr = kbuf + (nt * 16 + m16) * 64;
            short8 bk0 = *(const short8*)&kr[(q ^ rx) * 8];          // dims 0..31
            short8 bk1 = *(const short8*)&kr[((4 + q) ^ rx) * 8];    // dims 32..63
#define QKONE(AQ0, AQ1, DG, LRUN, PK)                                                  \
            do {                                                                       \
                f32x4 z = {0.f, 0.f, 0.f, 0.f};                                        \
                z = __builtin_amdgcn_mfma_f32_16x16x32_bf16(bk0, AQ0, z, 0, 0, 0);     \
                z = __builtin_amdgcn_mfma_f32_16x16x32_bf16(bk1, AQ1, z, 0, 0, 0);     \
                float e0, e1, e2, e3;                                                  \
                {                                                                      \
                    float s0 = z[0], s1 = z[1], s2 = z[2], s3 = z[3];                  \
                    if (DG) {                                                          \
                        int qi = w * 16 + m16, kb = nt * 16 + q * 4;                   \
                        if (kb + 0 > qi) s0 = -__builtin_inff();                       \
                        if (kb + 1 > qi) s1 = -__builtin_inff();                       \
                        if (kb + 2 > qi) s2 = -__builtin_inff();                       \
                        if (kb + 3 > qi) s3 = -__builtin_inff();                       \
                    }                                                                  \
                    e0 = __builtin_amdgcn_exp2f(s0); e1 = __builtin_amdgcn_exp2f(s1);  \
                    e2 = __builtin_amdgcn_exp2f(s2); e3 = __builtin_amdgcn_exp2f(s3);  \
                }                                                                      \
                LRUN += (e0 + e1) + (e2 + e3);                                         \
                PK[nt][0] = cvtpk_bf16(e0, e1);                                        \
                PK[nt][1] = cvtpk_bf16(e2, e3);                                        \
            } while (0)
            QKONE(aqA0, aqA1, dgA, lrunA, pkA);
            if (doB) QKONE(aqB0, aqB1, dgB, lrunB, pkB);
            if (doC) QKONE(aqC0, aqC1, dgC, lrunC, pkC);
            if (doD) QKONE(aqD0, aqD1, dgD, lrunD, pkD);
#undef QKONE
        }

        // PV A-fragments: permuted key order makes them the lane's own packed values.
#define PACK2(AP0, AP1, PK)                                                     \
        short8 AP0, AP1;                                                        \
        {                                                                       \
            int4v t0 = {PK[0][0], PK[0][1], PK[1][0], PK[1][1]};                \
            int4v t1 = {PK[2][0], PK[2][1], PK[3][0], PK[3][1]};                \
            AP0 = __builtin_bit_cast(short8, t0);                               \
            AP1 = __builtin_bit_cast(short8, t1);                               \
        }
        PACK2(apA0, apA1, pkA)
        PACK2(apB0, apB1, pkB)
        PACK2(apC0, apC1, pkC)
        PACK2(apD0, apD1, pkD)
#undef PACK2

        // ---- PV: V fragment shared 4-ways, 4x ds_read_b64 per d-tile ----
#pragma unroll
        for (int nt = 0; nt < 4; ++nt) {
            const unsigned short* vr = vbuf + (nt * 16 + m16) * 64;   // row = d
            int2v a0 = *(const int2v*)&vr[(((q >> 1) + 0) ^ rx) * 8 + (q & 1) * 4];
            int2v a1 = *(const int2v*)&vr[(((q >> 1) + 2) ^ rx) * 8 + (q & 1) * 4];
            int2v a2 = *(const int2v*)&vr[(((q >> 1) + 4) ^ rx) * 8 + (q & 1) * 4];
            int2v a3 = *(const int2v*)&vr[(((q >> 1) + 6) ^ rx) * 8 + (q & 1) * 4];
            int4v tv0 = {a0.x, a0.y, a1.x, a1.y};
            int4v tv1 = {a2.x, a2.y, a3.x, a3.y};
            short8 bv0 = __builtin_bit_cast(short8, tv0);
            short8 bv1 = __builtin_bit_cast(short8, tv1);
            accOA[nt] = __builtin_amdgcn_mfma_f32_16x16x32_bf16(apA0, bv0, accOA[nt], 0, 0, 0);
            accOA[nt] = __builtin_amdgcn_mfma_f32_16x16x32_bf16(apA1, bv1, accOA[nt], 0, 0, 0);
            if (doB) {
                accOB[nt] = __builtin_amdgcn_mfma_f32_16x16x32_bf16(apB0, bv0, accOB[nt], 0, 0, 0);
                accOB[nt] = __builtin_amdgcn_mfma_f32_16x16x32_bf16(apB1, bv1, accOB[nt], 0, 0, 0);
            }
            if (doC) {
                accOC[nt] = __builtin_amdgcn_mfma_f32_16x16x32_bf16(apC0, bv0, accOC[nt], 0, 0, 0);
                accOC[nt] = __builtin_amdgcn_mfma_f32_16x16x32_bf16(apC1, bv1, accOC[nt], 0, 0, 0);
            }
            if (doD) {
                accOD[nt] = __builtin_amdgcn_mfma_f32_16x16x32_bf16(apD0, bv0, accOD[nt], 0, 0, 0);
                accOD[nt] = __builtin_amdgcn_mfma_f32_16x16x32_bf16(apD1, bv1, accOD[nt], 0, 0, 0);
            }
        }
        __builtin_amdgcn_s_barrier();   // reads done before next iter overwrites buf^1
        cur ^= 1;
    }

    // denominators: reduce over the 4 q-lanes holding the same query (xor 16,32),
    // redistribute 1/l to output rows q*4+r, write O.
#define EPILOG(LRUN, ACC, TQ)                                                              \
    do {                                                                                   \
        float l = LRUN;                                                                    \
        l += __shfl_xor(l, 16); l += __shfl_xor(l, 32);                                    \
        float inv = 1.0f / l;                                                              \
        _Pragma("unroll")                                                                  \
        for (int r = 0; r < 4; ++r) {                                                      \
            float nv = __shfl(inv, q * 4 + r);                                             \
            _Pragma("unroll")                                                              \
            for (int nt = 0; nt < 4; ++nt) {                                               \
                int col = h * 64 + nt * 16 + m16;                                          \
                O[(size_t)(b * 2048 + (TQ) * 64 + w * 16 + q * 4 + r) * 2048 + col] =      \
                    f2bf(ACC[nt][r] * nv);                                                 \
            }                                                                              \
        }                                                                                  \
    } while (0)
    EPILOG(lrunA, accOA, tA);
    EPILOG(lrunB, accOB, tB);
    EPILOG(lrunC, accOC, tC);
    EPILOG(lrunD, accOD, tD);
#undef EPILOG
}

// ---------------- host launcher ----------------
extern "C" void kernel_launch(void* const* d_in, const int* in_sizes, int n_in,
                              void* d_out, int out_size, void* d_ws, size_t ws_size,
                              hipStream_t stream) {
    const float* hs = (const float*)d_in[0];   // (2,2048,2048)
    const float* sk = (const float*)d_in[1];   // (2,2048,32,64)
    const float* sv = (const float*)d_in[2];   // (2,2048,32,64)
    const float* wq = (const float*)d_in[3];   // (2048,2048)
    const float* wo = (const float*)d_in[4];   // (2048,2048)
    float* out = (float*)d_out;

    char* ws = (char*)d_ws;
    unsigned short* hid_b = (unsigned short*)(ws);                              // 16 MiB
    unsigned short* wq_b  = (unsigned short*)(ws + ((size_t)16 << 20));         //  8 MiB
    unsigned short* wo_b  = (unsigned short*)(ws + ((size_t)24 << 20));         //  8 MiB
    unsigned short* k_b   = (unsigned short*)(ws + ((size_t)32 << 20));         // 16 MiB
    unsigned short* vt_b  = (unsigned short*)(ws + ((size_t)48 << 20));         // 16 MiB
    unsigned short* q_b   = (unsigned short*)(ws + ((size_t)64 << 20));         // 16 MiB
    unsigned short* o_b   = (unsigned short*)(ws + ((size_t)80 << 20));         // 16 MiB

    cvt_tr<<<26624, 256, 0, stream>>>(hs, sk, wq, wo, sv, hid_b, k_b, wq_b, wo_b, vt_b);
    gemm_bt<true><<<dim3(32, 16), 256, 0, stream>>>(hid_b, wq_b, (void*)q_b, 4096, 2048, 2048);
    attn<<<512, 256, 0, stream>>>(q_b, k_b, vt_b, o_b);
    gemm_bt<false><<<dim3(32, 16), 256, 0, stream>>>(o_b, wo_b, (void*)out, 4096, 2048, 2048);
}